// Round 9
// baseline (226.420 us; speedup 1.0000x reference)
//
#include <hip/hip_runtime.h>

// 8-connected CCL on a 2048x2048 mask (prob > 0.5).
// Output int32: (component min flat index)+1 for fg, 0 for bg.
//
//   1. k_local   : per 128x64 tile (32KB LDS, 2 blocks/CU), ballot/run-based
//                  union-find. Labels init to ROW-GLOBAL run-start (no
//                  horizontal unions); vertical unions once per run-overlap
//                  segment; flatten via run-start pre-flatten + one LDS read.
//   2. k_seam    : cross-tile unions. One wave per 128-px seam chunk; ONE
//                  merge per (run,run) overlap segment. Merge = Playne-
//                  Stephens atomicMin walk (no finds, no halving writes --
//                  one coherent RMW per hop, monotone progress).
//   3. k_compress: READ-ONLY chase to root (tree is static here).

#define H 2048
#define W 2048
#define NPIX (H * W)
#define TSX 128           // tile width  (mask = 2 x u64)
#define TSY 64            // tile height
#define RPT 4             // rows per thread = TSY / 16

// ---------- global union-find merge (Playne-Stephens), 1-based parents ----
// Single atomicMin walk: tries to link the larger node under the smaller;
// on failure climbs to the observed parent. Parents only decrease and stay
// in-component; max(a,b) strictly decreases -> lock-free termination.
// Final roots = component minima. Atomics are inherently coherent (no
// stale-L1 hazard), so no explicit coherent loads are needed at all.
__device__ __forceinline__ void gunite(int* __restrict__ L, int a, int b) {
    while (a != b) {
        if (a > b) { int t = a; a = b; b = t; }   // a < b
        int old = atomicMin(&L[b], a + 1) - 1;    // try parent[b] = a
        if (old == b) return;                     // b was root: linked
        b = old;                                  // climb to old parent
    }
}

// ---------- local (LDS) union-find, 0-based, -1 = background ----------
__device__ __forceinline__ int lfind(volatile int* L, int a) {
    int n = L[a];
    while (n != a) { a = n; n = L[a]; }
    return a;
}

// find with atomicMin path-halving (safe under concurrent unions: parents
// only decrease and remain in-component)
__device__ __forceinline__ int lfind_h(int* L, int a) {
    volatile int* Lv = L;
    int n = Lv[a];
    while (n != a) {
        int g = Lv[n];
        if (g != n) atomicMin(&L[a], g);
        a = n; n = g;
    }
    return a;
}

__device__ __forceinline__ void lunite(int* L, int a, int b) {
    while (true) {
        a = lfind_h(L, a);
        b = lfind_h(L, b);
        if (a == b) return;
        if (a > b) { int t = a; a = b; b = t; }
        int old = atomicMin(&L[b], a);
        if (old == b) return;
        b = old;
    }
}

// run start (smallest s<=p with bits s..p all set; requires bit p set)
__device__ __forceinline__ int run_start64(unsigned long long m, int p) {
    if (p == 0) return 0;
    unsigned long long below = m << (64 - p);   // bit p-1 -> bit 63
    return p - __builtin_clzll(~below);         // minus count of leading ones
}

__device__ __forceinline__ int run_start128(unsigned long long u0,
                                            unsigned long long u1, int p) {
    if (p >= 64) {
        int s = run_start64(u1, p - 64) + 64;
        if (s == 64 && (u0 >> 63)) s = run_start64(u0, 63);  // continues left
        return s;
    }
    return run_start64(u0, p);
}

__device__ __forceinline__ int getbit128(unsigned long long u0,
                                         unsigned long long u1, int p) {
    if (p < 0 || p > 127) return 0;
    return (int)((p < 64 ? (u0 >> p) : (u1 >> (p - 64))) & 1ull);
}

__global__ __launch_bounds__(1024)
void k_local(const float* __restrict__ prob, int* __restrict__ lab) {
    __shared__ int slab[TSY * TSX];                       // 32 KB
    __shared__ unsigned long long mrow0[TSY], mrow1[TSY]; // 1 KB mask table
    const int x0 = blockIdx.x * TSX, y0 = blockIdx.y * TSY;
    const int lx = threadIdx.x;                 // 0..63 == lane
    const int ty = threadIdx.y;                 // 0..15

    unsigned long long rM0[RPT], rM1[RPT];
    int sA[RPT], sB[RPT];                       // run starts, register-cached

    // init: two ballots per row; label := row-global run start (kills all
    // horizontal unions, incl. across the 64-lane segment boundary)
    #pragma unroll
    for (int k = 0; k < RPT; ++k) {
        int ly = ty * RPT + k;
        const float* rowp = prob + (long)(y0 + ly) * W + x0;
        bool f0 = rowp[lx] > 0.5f;
        bool f1 = rowp[64 + lx] > 0.5f;
        unsigned long long m0 = __ballot(f0);
        unsigned long long m1 = __ballot(f1);
        rM0[k] = m0; rM1[k] = m1;
        int s0 = f0 ? run_start128(m0, m1, lx) : lx;
        int s1 = f1 ? run_start128(m0, m1, 64 + lx) : 64 + lx;
        sA[k] = s0; sB[k] = s1;
        slab[ly * TSX + lx]      = f0 ? ly * TSX + s0 : -1;
        slab[ly * TSX + 64 + lx] = f1 ? ly * TSX + s1 : -1;
        if (lx == 0) { mrow0[ly] = m0; mrow1[ly] = m1; }
    }
    __syncthreads();

    // vertical unions, once per (my-run, upper-segment) overlap.
    // Control uses ONLY register-cached / mask-table values (slab roots
    // mutate under concurrent lunite -- round-4 lesson).
    #pragma unroll
    for (int k = 0; k < RPT; ++k) {
        int ly = ty * RPT + k;
        if (ly == 0) continue;
        unsigned long long u0 = mrow0[ly - 1], u1 = mrow1[ly - 1];
        unsigned long long m0 = rM0[k], m1 = rM1[k];
        #pragma unroll
        for (int h = 0; h < 2; ++h) {
            int pos = h * 64 + lx;
            if (!getbit128(m0, m1, pos)) continue;
            int s = h ? sB[k] : sA[k];
            int mylab = ly * TSX + s;
            if (getbit128(u0, u1, pos)) {
                if (pos == s || !getbit128(u0, u1, pos - 1))
                    lunite(slab, mylab, (ly - 1) * TSX + run_start128(u0, u1, pos));
            } else {
                if (pos == s && getbit128(u0, u1, pos - 1))
                    lunite(slab, mylab, (ly - 1) * TSX + run_start128(u0, u1, pos - 1));
                bool isEnd = (pos == 127) || !getbit128(m0, m1, pos + 1);
                if (isEnd && getbit128(u0, u1, pos + 1))
                    lunite(slab, mylab, (ly - 1) * TSX + (pos + 1));
            }
        }
    }
    __syncthreads();

    // flatten step a: pre-flatten RUN-START entries only. Tree is static
    // now; plain stores write true roots.
    #pragma unroll
    for (int k = 0; k < RPT; ++k) {
        int ly = ty * RPT + k;
        unsigned long long m0 = rM0[k], m1 = rM1[k];
        if (((m0 >> lx) & 1) && sA[k] == lx) {
            int li = ly * TSX + lx;
            slab[li] = lfind(slab, li);
        }
        if (((m1 >> lx) & 1) && sB[k] == 64 + lx) {
            int li = ly * TSX + 64 + lx;
            slab[li] = lfind(slab, li);
        }
    }
    __syncthreads();

    // flatten step b: one LDS read at the register-cached run start
    // (same-run lanes hit one bank word -> broadcast).
    #pragma unroll
    for (int k = 0; k < RPT; ++k) {
        int ly = ty * RPT + k;
        unsigned long long m0 = rM0[k], m1 = rM1[k];
        int out0 = 0, out1 = 0;
        if ((m0 >> lx) & 1) {
            int r = slab[ly * TSX + sA[k]];
            out0 = (y0 + (r >> 7)) * W + (x0 + (r & 127)) + 1;
        }
        if ((m1 >> lx) & 1) {
            int r = slab[ly * TSX + sB[k]];
            out1 = (y0 + (r >> 7)) * W + (x0 + (r & 127)) + 1;
        }
        lab[(long)(y0 + ly) * W + x0 + lx]      = out0;
        lab[(long)(y0 + ly) * W + x0 + 64 + lx] = out1;
    }
}

// Cross-tile seam merge. 736 wave-tasks: 240 vertical (15 seam columns at
// x=128c, 16 chunks of 128 rows) + 496 horizontal (31 seam rows at y=64k,
// 16 chunks of 128 cols). One gunite per (B-run, A-run) overlap segment:
//   covered    : leftmost pos of the A-segment inside my run
//   left-touch : my run start, A set only at pos-1 (in-chunk)
//   right-touch: my run end,  A set only at pos+1 (in-chunk)
// Chunks crossing perpendicular tile boundaries stay correct by
// transitivity (perpendicular seam unions supply the intra-run links).
// Concurrently-tightened label entries are safe to read: atomicMin only
// replaces a parent with a same-component ancestor.
__global__ __launch_bounds__(256)
void k_seam(int* __restrict__ lab) {
    int gtid = blockIdx.x * blockDim.x + threadIdx.x;
    int task = gtid >> 6;
    int lane = gtid & 63;
    bool vertical = task < 240;
    int t = vertical ? task : task - 240;
    int seam, chunk;

    long baseB, baseA, step;
    int B0, B1, A0, A1;
    if (vertical) {
        seam = t >> 4; chunk = t & 15;
        int x = (seam + 1) << 7;           // seam column
        int ybase = chunk << 7;            // 128-row chunk
        baseB = (long)ybase * W + x;
        baseA = baseB - 1;
        step = W;
        B0 = lab[baseB + (long)lane * W];
        B1 = lab[baseB + (long)(lane + 64) * W];
        A0 = lab[baseA + (long)lane * W];
        A1 = lab[baseA + (long)(lane + 64) * W];
    } else {
        seam = t >> 4; chunk = t & 15;     // seam 0..30
        int y = (seam + 1) << 6;           // seam row (every 64)
        int xbase = chunk << 7;
        baseB = (long)y * W + xbase;
        baseA = baseB - W;
        step = 1;
        B0 = lab[baseB + lane];
        B1 = lab[baseB + 64 + lane];
        A0 = lab[baseA + lane];
        A1 = lab[baseA + 64 + lane];
    }
    unsigned long long m0 = __ballot(B0 != 0), m1 = __ballot(B1 != 0);
    unsigned long long u0 = __ballot(A0 != 0), u1 = __ballot(A1 != 0);

    #pragma unroll
    for (int h = 0; h < 2; ++h) {
        int pos = (h << 6) | lane;
        if (!getbit128(m0, m1, pos)) continue;
        int myB = h ? B1 : B0;
        int s = run_start128(m0, m1, pos);
        if (getbit128(u0, u1, pos)) {
            if (pos == s || !getbit128(u0, u1, pos - 1)) {
                int tgt = h ? A1 : A0;
                gunite(lab, myB - 1, tgt - 1);
            }
        } else {
            if (pos == s && pos > 0 && getbit128(u0, u1, pos - 1)) {
                int tgt = lab[baseA + (long)(pos - 1) * step];
                gunite(lab, myB - 1, tgt - 1);
            }
            bool isEnd = (pos == 127) || !getbit128(m0, m1, pos + 1);
            if (isEnd && pos < 127 && getbit128(u0, u1, pos + 1)) {
                int tgt = lab[baseA + (long)(pos + 1) * step];
                gunite(lab, myB - 1, tgt - 1);
            }
        }
    }

    // corner diagonal links (horizontal chunks only, edge lanes)
    if (!vertical && lane == 0) {
        int y = (seam + 1) << 6;
        int xbase = chunk << 7;
        if (xbase > 0 && (m0 & 1) && !(u0 & 1)) {          // NW corner
            int tgt = lab[(long)(y - 1) * W + xbase - 1];
            if (tgt) gunite(lab, B0 - 1, tgt - 1);
        }
        if (xbase + 128 < W && ((m1 >> 63) & 1) && !((u1 >> 63) & 1)) {  // NE
            int tgt = lab[(long)(y - 1) * W + xbase + 128];
            if (tgt) {
                int b127 = lab[(long)y * W + xbase + 127];
                gunite(lab, b127 - 1, tgt - 1);
            }
        }
    }
}

// READ-ONLY compress: the union-find tree is static in this kernel, so no
// halving writes (4M atomicMins aimed at a few thousand root cachelines
// would serialize). Plain loads: kernel-launch boundary invalidates stale
// L1; in-kernel writes only store FINAL root values, which are themselves
// valid ancestors for any concurrent reader.
__global__ __launch_bounds__(256)
void k_compress(int* __restrict__ lab) {
    int i = blockIdx.x * blockDim.x + threadIdx.x;
    if (i >= NPIX) return;
    int v = lab[i];
    if (v == 0) return;                  // bg
    int a = v - 1;
    int n = lab[a];
    while (n != a + 1) { a = n - 1; n = lab[a]; }
    if (a + 1 != v) lab[i] = a + 1;      // root+1 is the component min
}

extern "C" void kernel_launch(void* const* d_in, const int* in_sizes, int n_in,
                              void* d_out, int out_size, void* d_ws, size_t ws_size,
                              hipStream_t stream) {
    const float* prob = (const float*)d_in[0];
    int* lab = (int*)d_out;

    dim3 lgrid(W / TSX, H / TSY);        // 16 x 32 = 512 blocks (2/CU)
    dim3 lblock(64, 16);                 // 1024 threads, 16 waves
    k_local<<<lgrid, lblock, 0, stream>>>(prob, lab);

    // 736 wave-tasks * 64 lanes = 47104 threads = 184 blocks exactly
    k_seam<<<184, 256, 0, stream>>>(lab);

    k_compress<<<NPIX / 256, 256, 0, stream>>>(lab);
}

// Round 10
// 105.788 us; speedup vs baseline: 2.1403x; 2.1403x over previous
//
#include <hip/hip_runtime.h>

// 8-connected CCL on a 2048x2048 mask (prob > 0.5).
// Output int32: (component min flat index)+1 for fg, 0 for bg.
//
//   1. k_local   : per 128x64 tile (32KB LDS, 2 blocks/CU), ballot/run-based
//                  union-find. Labels init to ROW-GLOBAL run-start (no
//                  horizontal unions); vertical unions once per run-overlap
//                  segment; flatten via run-start pre-flatten + one LDS read.
//   2. k_seam    : cross-tile unions, 64-px chunks (one wave each), ONE
//                  gunite per (run,run) overlap segment. gunite = path-
//                  halving find + attach (round-8 proven; the r9 atomicMin-
//                  walk regressed 3x -- RMW per hop on hot chains).
//   3. k_compress: READ-ONLY chase to root (tree is static here).

#define H 2048
#define W 2048
#define NPIX (H * W)
#define TSX 128           // tile width  (mask = 2 x u64)
#define TSY 64            // tile height
#define RPT 4             // rows per thread = TSY / 16

__device__ __forceinline__ int aload(const int* p) {
    // coherent (agent-scope) load: bypasses per-CU L1, reads L2 truth.
    return __hip_atomic_load(p, __ATOMIC_RELAXED, __HIP_MEMORY_SCOPE_AGENT);
}

// ---------- global union-find, 1-based parents, path-halving find ----------
__device__ __forceinline__ int gfind(int* __restrict__ L, int a) {
    int n = aload(&L[a]);
    while (n != a + 1) {
        int p = n - 1;
        int g = aload(&L[p]);             // grandparent+1
        // halving MUST be atomicMin: plain store could overwrite a
        // concurrent union's smaller parent. g is same-component & smaller.
        if (g != n) atomicMin(&L[a], g);
        a = p; n = g;
    }
    return a;
}

__device__ __forceinline__ void gunite(int* __restrict__ L, int a, int b) {
    while (true) {
        a = gfind(L, a);
        b = gfind(L, b);
        if (a == b) return;
        if (a > b) { int t = a; a = b; b = t; }
        int old = atomicMin(&L[b], a + 1);
        if (old == b + 1) return;   // attached larger root under smaller
        b = old - 1;                // raced; retry from observed parent
    }
}

// ---------- local (LDS) union-find, 0-based, -1 = background ----------
__device__ __forceinline__ int lfind(volatile int* L, int a) {
    int n = L[a];
    while (n != a) { a = n; n = L[a]; }
    return a;
}

// find with atomicMin path-halving (safe under concurrent unions: parents
// only decrease and remain in-component)
__device__ __forceinline__ int lfind_h(int* L, int a) {
    volatile int* Lv = L;
    int n = Lv[a];
    while (n != a) {
        int g = Lv[n];
        if (g != n) atomicMin(&L[a], g);
        a = n; n = g;
    }
    return a;
}

__device__ __forceinline__ void lunite(int* L, int a, int b) {
    while (true) {
        a = lfind_h(L, a);
        b = lfind_h(L, b);
        if (a == b) return;
        if (a > b) { int t = a; a = b; b = t; }
        int old = atomicMin(&L[b], a);
        if (old == b) return;
        b = old;
    }
}

// run start (smallest s<=p with bits s..p all set; requires bit p set)
__device__ __forceinline__ int run_start64(unsigned long long m, int p) {
    if (p == 0) return 0;
    unsigned long long below = m << (64 - p);   // bit p-1 -> bit 63
    return p - __builtin_clzll(~below);         // minus count of leading ones
}

__device__ __forceinline__ int run_start128(unsigned long long u0,
                                            unsigned long long u1, int p) {
    if (p >= 64) {
        int s = run_start64(u1, p - 64) + 64;
        if (s == 64 && (u0 >> 63)) s = run_start64(u0, 63);  // continues left
        return s;
    }
    return run_start64(u0, p);
}

__device__ __forceinline__ int getbit128(unsigned long long u0,
                                         unsigned long long u1, int p) {
    if (p < 0 || p > 127) return 0;
    return (int)((p < 64 ? (u0 >> p) : (u1 >> (p - 64))) & 1ull);
}

__global__ __launch_bounds__(1024)
void k_local(const float* __restrict__ prob, int* __restrict__ lab) {
    __shared__ int slab[TSY * TSX];                       // 32 KB
    __shared__ unsigned long long mrow0[TSY], mrow1[TSY]; // 1 KB mask table
    const int x0 = blockIdx.x * TSX, y0 = blockIdx.y * TSY;
    const int lx = threadIdx.x;                 // 0..63 == lane
    const int ty = threadIdx.y;                 // 0..15

    unsigned long long rM0[RPT], rM1[RPT];
    int sA[RPT], sB[RPT];                       // run starts, register-cached

    // init: two ballots per row; label := row-global run start (kills all
    // horizontal unions, incl. across the 64-lane segment boundary)
    #pragma unroll
    for (int k = 0; k < RPT; ++k) {
        int ly = ty * RPT + k;
        const float* rowp = prob + (long)(y0 + ly) * W + x0;
        bool f0 = rowp[lx] > 0.5f;
        bool f1 = rowp[64 + lx] > 0.5f;
        unsigned long long m0 = __ballot(f0);
        unsigned long long m1 = __ballot(f1);
        rM0[k] = m0; rM1[k] = m1;
        int s0 = f0 ? run_start128(m0, m1, lx) : lx;
        int s1 = f1 ? run_start128(m0, m1, 64 + lx) : 64 + lx;
        sA[k] = s0; sB[k] = s1;
        slab[ly * TSX + lx]      = f0 ? ly * TSX + s0 : -1;
        slab[ly * TSX + 64 + lx] = f1 ? ly * TSX + s1 : -1;
        if (lx == 0) { mrow0[ly] = m0; mrow1[ly] = m1; }
    }
    __syncthreads();

    // vertical unions, once per (my-run, upper-segment) overlap.
    // Control uses ONLY register-cached / mask-table values (slab roots
    // mutate under concurrent lunite -- round-4 lesson).
    #pragma unroll
    for (int k = 0; k < RPT; ++k) {
        int ly = ty * RPT + k;
        if (ly == 0) continue;
        unsigned long long u0 = mrow0[ly - 1], u1 = mrow1[ly - 1];
        unsigned long long m0 = rM0[k], m1 = rM1[k];
        #pragma unroll
        for (int h = 0; h < 2; ++h) {
            int pos = h * 64 + lx;
            if (!getbit128(m0, m1, pos)) continue;
            int s = h ? sB[k] : sA[k];
            int mylab = ly * TSX + s;
            if (getbit128(u0, u1, pos)) {
                if (pos == s || !getbit128(u0, u1, pos - 1))
                    lunite(slab, mylab, (ly - 1) * TSX + run_start128(u0, u1, pos));
            } else {
                if (pos == s && getbit128(u0, u1, pos - 1))
                    lunite(slab, mylab, (ly - 1) * TSX + run_start128(u0, u1, pos - 1));
                bool isEnd = (pos == 127) || !getbit128(m0, m1, pos + 1);
                if (isEnd && getbit128(u0, u1, pos + 1))
                    lunite(slab, mylab, (ly - 1) * TSX + (pos + 1));
            }
        }
    }
    __syncthreads();

    // flatten step a: pre-flatten RUN-START entries only. Tree is static
    // now; plain stores write true roots.
    #pragma unroll
    for (int k = 0; k < RPT; ++k) {
        int ly = ty * RPT + k;
        unsigned long long m0 = rM0[k], m1 = rM1[k];
        if (((m0 >> lx) & 1) && sA[k] == lx) {
            int li = ly * TSX + lx;
            slab[li] = lfind(slab, li);
        }
        if (((m1 >> lx) & 1) && sB[k] == 64 + lx) {
            int li = ly * TSX + 64 + lx;
            slab[li] = lfind(slab, li);
        }
    }
    __syncthreads();

    // flatten step b: one LDS read at the register-cached run start
    // (same-run lanes hit one bank word -> broadcast).
    #pragma unroll
    for (int k = 0; k < RPT; ++k) {
        int ly = ty * RPT + k;
        unsigned long long m0 = rM0[k], m1 = rM1[k];
        int out0 = 0, out1 = 0;
        if ((m0 >> lx) & 1) {
            int r = slab[ly * TSX + sA[k]];
            out0 = (y0 + (r >> 7)) * W + (x0 + (r & 127)) + 1;
        }
        if ((m1 >> lx) & 1) {
            int r = slab[ly * TSX + sB[k]];
            out1 = (y0 + (r >> 7)) * W + (x0 + (r & 127)) + 1;
        }
        lab[(long)(y0 + ly) * W + x0 + lx]      = out0;
        lab[(long)(y0 + ly) * W + x0 + 64 + lx] = out1;
    }
}

// Cross-tile seam merge, 64-px chunks (one wave64 each).
// 1472 wave-tasks: 480 vertical (15 seam cols x=128c, 32 chunks of 64 rows,
// aligned to the 64-row tile bands) + 992 horizontal (31 seam rows y=64k,
// 32 chunks of 64 cols). Single-u64 masks. One gunite per (B-run, A-run)
// overlap segment:
//   covered    : leftmost pos of the A-segment inside my run
//   left-touch : my run start, A set only at pos-1 (target via __shfl)
//   right-touch: my run end,  A set only at pos+1 (target via __shfl)
// Runs crossing chunk/tile boundaries are correct by transitivity (the
// perpendicular seam's unions supply the intra-run links). Out-of-chunk
// corner contacts are handled by the horizontal chunks' edge lanes (every
// chunk boundary x=64m; covers all 4-tile-corner diagonals since vertical
// chunk edges y=64m lie ON horizontal seams).
__global__ __launch_bounds__(256)
void k_seam(int* __restrict__ lab) {
    int gtid = blockIdx.x * blockDim.x + threadIdx.x;
    int task = gtid >> 6;
    int lane = gtid & 63;
    bool vertical = task < 480;
    int t = vertical ? task : task - 480;
    int seam = t >> 5, chunk = t & 31;

    long baseB, baseA;
    int B, A;
    int y_h = 0, xb_h = 0;
    if (vertical) {
        int x = (seam + 1) << 7;           // seam column
        int ybase = chunk << 6;            // 64-row chunk, tile-band aligned
        baseB = (long)ybase * W + x;
        baseA = baseB - 1;
        B = lab[baseB + (long)lane * W];
        A = lab[baseA + (long)lane * W];
    } else {
        y_h = (seam + 1) << 6;             // seam row (every 64)
        xb_h = chunk << 6;                 // 64-col chunk
        baseB = (long)y_h * W + xb_h;
        baseA = baseB - W;
        B = lab[baseB + lane];
        A = lab[baseA + lane];
    }
    // hoist cross-lane moves while ALL lanes are active
    int Am1 = __shfl(A, (lane == 0) ? 0 : lane - 1);
    int Ap1 = __shfl(A, (lane == 63) ? 63 : lane + 1);
    int B63 = __shfl(B, 63);

    unsigned long long m = __ballot(B != 0);
    unsigned long long u = __ballot(A != 0);

    if (B) {
        int s = run_start64(m, lane);
        if ((u >> lane) & 1) {
            if (lane == s || !((u >> (lane - 1)) & 1))
                gunite(lab, B - 1, A - 1);
        } else {
            if (lane == s && lane > 0 && ((u >> (lane - 1)) & 1))
                gunite(lab, B - 1, Am1 - 1);
            bool isEnd = (lane == 63) || !((m >> (lane + 1)) & 1);
            if (isEnd && lane < 63 && ((u >> (lane + 1)) & 1))
                gunite(lab, B - 1, Ap1 - 1);
        }
    }

    // corner diagonal links (horizontal chunks only, edge lanes)
    if (!vertical && lane == 0) {
        if (xb_h > 0 && (m & 1) && !(u & 1)) {             // NW corner
            int tgt = lab[(long)(y_h - 1) * W + xb_h - 1];
            if (tgt) gunite(lab, B - 1, tgt - 1);
        }
        if (xb_h + 64 < W && ((m >> 63) & 1) && !((u >> 63) & 1)) {  // NE
            int tgt = lab[(long)(y_h - 1) * W + xb_h + 64];
            if (tgt) gunite(lab, B63 - 1, tgt - 1);
        }
    }
}

// READ-ONLY compress: the union-find tree is static in this kernel, so no
// halving writes (4M atomicMins aimed at a few thousand root cachelines
// would serialize). Plain loads: kernel-launch boundary invalidates stale
// L1; in-kernel writes only store FINAL root values, which are themselves
// valid ancestors for any concurrent reader.
__global__ __launch_bounds__(256)
void k_compress(int* __restrict__ lab) {
    int i = blockIdx.x * blockDim.x + threadIdx.x;
    if (i >= NPIX) return;
    int v = lab[i];
    if (v == 0) return;                  // bg
    int a = v - 1;
    int n = lab[a];
    while (n != a + 1) { a = n - 1; n = lab[a]; }
    if (a + 1 != v) lab[i] = a + 1;      // root+1 is the component min
}

extern "C" void kernel_launch(void* const* d_in, const int* in_sizes, int n_in,
                              void* d_out, int out_size, void* d_ws, size_t ws_size,
                              hipStream_t stream) {
    const float* prob = (const float*)d_in[0];
    int* lab = (int*)d_out;

    dim3 lgrid(W / TSX, H / TSY);        // 16 x 32 = 512 blocks (2/CU)
    dim3 lblock(64, 16);                 // 1024 threads, 16 waves
    k_local<<<lgrid, lblock, 0, stream>>>(prob, lab);

    // 1472 wave-tasks * 64 lanes = 94208 threads = 368 blocks exactly
    k_seam<<<368, 256, 0, stream>>>(lab);

    k_compress<<<NPIX / 256, 256, 0, stream>>>(lab);
}

// Round 11
// 75.810 us; speedup vs baseline: 2.9867x; 1.3954x over previous
//
#include <hip/hip_runtime.h>

// 8-connected CCL on a 2048x2048 mask (prob > 0.5).
// Output int32: (component min flat index)+1 for fg, 0 for bg.
//
//   1. k_local   : per 128x64 tile (32KB LDS, 2 blocks/CU), ballot/run-based
//                  union-find. Labels init to ROW-GLOBAL run-start (no
//                  horizontal unions); vertical unions once per run-overlap
//                  segment; flatten via run-start pre-flatten + one LDS read.
//   2. k_seam    : cross-tile unions, 128-px chunks (round-8 structure --
//                  measured best). gunite = path-halving find + attach.
//                  Finds use PLAIN loads (L1-cacheable): stale values are
//                  correctness-safe (see gunite comment), and the hot
//                  funnel-top entries become ~20cy L1 hits instead of
//                  serialized ~220cy agent-scope L2 point-reads.
//   3. k_compress: READ-ONLY chase to root (tree is static here).

#define H 2048
#define W 2048
#define NPIX (H * W)
#define TSX 128           // tile width  (mask = 2 x u64)
#define TSY 64            // tile height
#define RPT 4             // rows per thread = TSY / 16

// ---------- global union-find, 1-based parents, path-halving find ----------
// PLAIN loads: L1 may serve stale parents. This is SAFE:
//  - a stale parent is a past ancestor -> same component (parents only
//    decrease, staying in-component);
//  - halving atomicMin(&L[a], g) with stale g only lowers toward a valid
//    ancestor (atomicMin never raises);
//  - a stale "root" r is caught at attach time: atomicMin is coherent, and
//    if it overwrote a real parent c (old=c+1 != b+1), the caller CONTINUES
//    WITH c, re-uniting a~c and thereby restoring the b~c relation through
//    a (Komura retry invariant). Never re-find b after a failed attach --
//    the continuation with the observed old value is what repairs the link.
__device__ __forceinline__ int gfind(int* __restrict__ L, int a) {
    int n = L[a];
    while (n != a + 1) {
        int p = n - 1;
        int g = L[p];                     // grandparent+1 (possibly stale)
        // halving MUST be atomicMin: plain store could overwrite a
        // concurrent union's smaller parent. g is same-component & smaller.
        if (g != n) atomicMin(&L[a], g);
        a = p; n = g;
    }
    return a;
}

__device__ __forceinline__ void gunite(int* __restrict__ L, int a, int b) {
    while (true) {
        a = gfind(L, a);
        b = gfind(L, b);
        if (a == b) return;
        if (a > b) { int t = a; a = b; b = t; }
        int old = atomicMin(&L[b], a + 1);
        if (old == b + 1) return;   // attached larger root under smaller
        b = old - 1;                // raced/stale; continue from observed
    }                               // parent (repairs any severed link)
}

// ---------- local (LDS) union-find, 0-based, -1 = background ----------
__device__ __forceinline__ int lfind(volatile int* L, int a) {
    int n = L[a];
    while (n != a) { a = n; n = L[a]; }
    return a;
}

// find with atomicMin path-halving (safe under concurrent unions: parents
// only decrease and remain in-component)
__device__ __forceinline__ int lfind_h(int* L, int a) {
    volatile int* Lv = L;
    int n = Lv[a];
    while (n != a) {
        int g = Lv[n];
        if (g != n) atomicMin(&L[a], g);
        a = n; n = g;
    }
    return a;
}

__device__ __forceinline__ void lunite(int* L, int a, int b) {
    while (true) {
        a = lfind_h(L, a);
        b = lfind_h(L, b);
        if (a == b) return;
        if (a > b) { int t = a; a = b; b = t; }
        int old = atomicMin(&L[b], a);
        if (old == b) return;
        b = old;
    }
}

// run start (smallest s<=p with bits s..p all set; requires bit p set)
__device__ __forceinline__ int run_start64(unsigned long long m, int p) {
    if (p == 0) return 0;
    unsigned long long below = m << (64 - p);   // bit p-1 -> bit 63
    return p - __builtin_clzll(~below);         // minus count of leading ones
}

__device__ __forceinline__ int run_start128(unsigned long long u0,
                                            unsigned long long u1, int p) {
    if (p >= 64) {
        int s = run_start64(u1, p - 64) + 64;
        if (s == 64 && (u0 >> 63)) s = run_start64(u0, 63);  // continues left
        return s;
    }
    return run_start64(u0, p);
}

__device__ __forceinline__ int getbit128(unsigned long long u0,
                                         unsigned long long u1, int p) {
    if (p < 0 || p > 127) return 0;
    return (int)((p < 64 ? (u0 >> p) : (u1 >> (p - 64))) & 1ull);
}

__global__ __launch_bounds__(1024)
void k_local(const float* __restrict__ prob, int* __restrict__ lab) {
    __shared__ int slab[TSY * TSX];                       // 32 KB
    __shared__ unsigned long long mrow0[TSY], mrow1[TSY]; // 1 KB mask table
    const int x0 = blockIdx.x * TSX, y0 = blockIdx.y * TSY;
    const int lx = threadIdx.x;                 // 0..63 == lane
    const int ty = threadIdx.y;                 // 0..15

    unsigned long long rM0[RPT], rM1[RPT];
    int sA[RPT], sB[RPT];                       // run starts, register-cached

    // init: two ballots per row; label := row-global run start (kills all
    // horizontal unions, incl. across the 64-lane segment boundary)
    #pragma unroll
    for (int k = 0; k < RPT; ++k) {
        int ly = ty * RPT + k;
        const float* rowp = prob + (long)(y0 + ly) * W + x0;
        bool f0 = rowp[lx] > 0.5f;
        bool f1 = rowp[64 + lx] > 0.5f;
        unsigned long long m0 = __ballot(f0);
        unsigned long long m1 = __ballot(f1);
        rM0[k] = m0; rM1[k] = m1;
        int s0 = f0 ? run_start128(m0, m1, lx) : lx;
        int s1 = f1 ? run_start128(m0, m1, 64 + lx) : 64 + lx;
        sA[k] = s0; sB[k] = s1;
        slab[ly * TSX + lx]      = f0 ? ly * TSX + s0 : -1;
        slab[ly * TSX + 64 + lx] = f1 ? ly * TSX + s1 : -1;
        if (lx == 0) { mrow0[ly] = m0; mrow1[ly] = m1; }
    }
    __syncthreads();

    // vertical unions, once per (my-run, upper-segment) overlap.
    // Control uses ONLY register-cached / mask-table values (slab roots
    // mutate under concurrent lunite -- round-4 lesson).
    #pragma unroll
    for (int k = 0; k < RPT; ++k) {
        int ly = ty * RPT + k;
        if (ly == 0) continue;
        unsigned long long u0 = mrow0[ly - 1], u1 = mrow1[ly - 1];
        unsigned long long m0 = rM0[k], m1 = rM1[k];
        #pragma unroll
        for (int h = 0; h < 2; ++h) {
            int pos = h * 64 + lx;
            if (!getbit128(m0, m1, pos)) continue;
            int s = h ? sB[k] : sA[k];
            int mylab = ly * TSX + s;
            if (getbit128(u0, u1, pos)) {
                if (pos == s || !getbit128(u0, u1, pos - 1))
                    lunite(slab, mylab, (ly - 1) * TSX + run_start128(u0, u1, pos));
            } else {
                if (pos == s && getbit128(u0, u1, pos - 1))
                    lunite(slab, mylab, (ly - 1) * TSX + run_start128(u0, u1, pos - 1));
                bool isEnd = (pos == 127) || !getbit128(m0, m1, pos + 1);
                if (isEnd && getbit128(u0, u1, pos + 1))
                    lunite(slab, mylab, (ly - 1) * TSX + (pos + 1));
            }
        }
    }
    __syncthreads();

    // flatten step a: pre-flatten RUN-START entries only. Tree is static
    // now; plain stores write true roots.
    #pragma unroll
    for (int k = 0; k < RPT; ++k) {
        int ly = ty * RPT + k;
        unsigned long long m0 = rM0[k], m1 = rM1[k];
        if (((m0 >> lx) & 1) && sA[k] == lx) {
            int li = ly * TSX + lx;
            slab[li] = lfind(slab, li);
        }
        if (((m1 >> lx) & 1) && sB[k] == 64 + lx) {
            int li = ly * TSX + 64 + lx;
            slab[li] = lfind(slab, li);
        }
    }
    __syncthreads();

    // flatten step b: one LDS read at the register-cached run start
    // (same-run lanes hit one bank word -> broadcast).
    #pragma unroll
    for (int k = 0; k < RPT; ++k) {
        int ly = ty * RPT + k;
        unsigned long long m0 = rM0[k], m1 = rM1[k];
        int out0 = 0, out1 = 0;
        if ((m0 >> lx) & 1) {
            int r = slab[ly * TSX + sA[k]];
            out0 = (y0 + (r >> 7)) * W + (x0 + (r & 127)) + 1;
        }
        if ((m1 >> lx) & 1) {
            int r = slab[ly * TSX + sB[k]];
            out1 = (y0 + (r >> 7)) * W + (x0 + (r & 127)) + 1;
        }
        lab[(long)(y0 + ly) * W + x0 + lx]      = out0;
        lab[(long)(y0 + ly) * W + x0 + 64 + lx] = out1;
    }
}

// Cross-tile seam merge (round-8 structure). 736 wave-tasks: 240 vertical
// (15 seam columns at x=128c, 16 chunks of 128 rows) + 496 horizontal
// (31 seam rows at y=64k, 16 chunks of 128 cols). One gunite per
// (B-run, A-run) overlap segment:
//   covered    : leftmost pos of the A-segment inside my run
//   left-touch : my run start, A set only at pos-1 (in-chunk)
//   right-touch: my run end,  A set only at pos+1 (in-chunk)
// Chunks crossing perpendicular tile boundaries stay correct by
// transitivity (perpendicular seam unions supply the intra-run links).
// Concurrently-tightened label entries are safe to read: atomicMin only
// replaces a parent with a same-component ancestor.
__global__ __launch_bounds__(256)
void k_seam(int* __restrict__ lab) {
    int gtid = blockIdx.x * blockDim.x + threadIdx.x;
    int task = gtid >> 6;
    int lane = gtid & 63;
    bool vertical = task < 240;
    int t = vertical ? task : task - 240;
    int seam, chunk;

    long baseB, baseA, step;
    int B0, B1, A0, A1;
    if (vertical) {
        seam = t >> 4; chunk = t & 15;
        int x = (seam + 1) << 7;           // seam column
        int ybase = chunk << 7;            // 128-row chunk
        baseB = (long)ybase * W + x;
        baseA = baseB - 1;
        step = W;
        B0 = lab[baseB + (long)lane * W];
        B1 = lab[baseB + (long)(lane + 64) * W];
        A0 = lab[baseA + (long)lane * W];
        A1 = lab[baseA + (long)(lane + 64) * W];
    } else {
        seam = t >> 4; chunk = t & 15;     // seam 0..30
        int y = (seam + 1) << 6;           // seam row (every 64)
        int xbase = chunk << 7;
        baseB = (long)y * W + xbase;
        baseA = baseB - W;
        step = 1;
        B0 = lab[baseB + lane];
        B1 = lab[baseB + 64 + lane];
        A0 = lab[baseA + lane];
        A1 = lab[baseA + 64 + lane];
    }
    unsigned long long m0 = __ballot(B0 != 0), m1 = __ballot(B1 != 0);
    unsigned long long u0 = __ballot(A0 != 0), u1 = __ballot(A1 != 0);

    #pragma unroll
    for (int h = 0; h < 2; ++h) {
        int pos = (h << 6) | lane;
        if (!getbit128(m0, m1, pos)) continue;
        int myB = h ? B1 : B0;
        int s = run_start128(m0, m1, pos);
        if (getbit128(u0, u1, pos)) {
            if (pos == s || !getbit128(u0, u1, pos - 1)) {
                int tgt = h ? A1 : A0;
                gunite(lab, myB - 1, tgt - 1);
            }
        } else {
            if (pos == s && pos > 0 && getbit128(u0, u1, pos - 1)) {
                int tgt = lab[baseA + (long)(pos - 1) * step];
                gunite(lab, myB - 1, tgt - 1);
            }
            bool isEnd = (pos == 127) || !getbit128(m0, m1, pos + 1);
            if (isEnd && pos < 127 && getbit128(u0, u1, pos + 1)) {
                int tgt = lab[baseA + (long)(pos + 1) * step];
                gunite(lab, myB - 1, tgt - 1);
            }
        }
    }

    // corner diagonal links (horizontal chunks only, edge lanes)
    if (!vertical && lane == 0) {
        int y = (seam + 1) << 6;
        int xbase = chunk << 7;
        if (xbase > 0 && (m0 & 1) && !(u0 & 1)) {          // NW corner
            int tgt = lab[(long)(y - 1) * W + xbase - 1];
            if (tgt) gunite(lab, B0 - 1, tgt - 1);
        }
        if (xbase + 128 < W && ((m1 >> 63) & 1) && !((u1 >> 63) & 1)) {  // NE
            int tgt = lab[(long)(y - 1) * W + xbase + 128];
            if (tgt) {
                int b127 = lab[(long)y * W + xbase + 127];
                gunite(lab, b127 - 1, tgt - 1);
            }
        }
    }
}

// READ-ONLY compress: the union-find tree is static in this kernel, so no
// halving writes (4M atomicMins aimed at a few thousand root cachelines
// would serialize). Plain loads: kernel-launch boundary invalidates stale
// L1; in-kernel writes only store FINAL root values, which are themselves
// valid ancestors for any concurrent reader.
__global__ __launch_bounds__(256)
void k_compress(int* __restrict__ lab) {
    int i = blockIdx.x * blockDim.x + threadIdx.x;
    if (i >= NPIX) return;
    int v = lab[i];
    if (v == 0) return;                  // bg
    int a = v - 1;
    int n = lab[a];
    while (n != a + 1) { a = n - 1; n = lab[a]; }
    if (a + 1 != v) lab[i] = a + 1;      // root+1 is the component min
}

extern "C" void kernel_launch(void* const* d_in, const int* in_sizes, int n_in,
                              void* d_out, int out_size, void* d_ws, size_t ws_size,
                              hipStream_t stream) {
    const float* prob = (const float*)d_in[0];
    int* lab = (int*)d_out;

    dim3 lgrid(W / TSX, H / TSY);        // 16 x 32 = 512 blocks (2/CU)
    dim3 lblock(64, 16);                 // 1024 threads, 16 waves
    k_local<<<lgrid, lblock, 0, stream>>>(prob, lab);

    // 736 wave-tasks * 64 lanes = 47104 threads = 184 blocks exactly
    k_seam<<<184, 256, 0, stream>>>(lab);

    k_compress<<<NPIX / 256, 256, 0, stream>>>(lab);
}

// Round 12
// 75.721 us; speedup vs baseline: 2.9902x; 1.0012x over previous
//
#include <hip/hip_runtime.h>

// 8-connected CCL on a 2048x2048 mask (prob > 0.5).
// Output int32: (component min flat index)+1 for fg, 0 for bg.
//
//   1. k_local   : per 128x64 tile (32KB LDS, 2 blocks/CU), ballot/run-based
//                  union-find. Labels init to ROW-GLOBAL run-start (no
//                  horizontal unions); vertical unions once per run-overlap
//                  segment; flatten via run-start pre-flatten + one LDS read.
//                  Tile-edge labels are ALSO packed into a d_ws sidecar so
//                  k_seam's vertical loads are coalesced.
//   2. k_seam    : cross-tile unions, 128-px chunks. One gunite per
//                  (run,run) overlap segment. gunite = path-halving find +
//                  attach, PLAIN L1 loads (stale-safe, round-11 proven).
//                  Vertical seams read the contiguous sidecar, not stride-W.
//   3. k_compress: READ-ONLY chase to root (tree is static here).

#define H 2048
#define W 2048
#define NPIX (H * W)
#define TSX 128           // tile width  (mask = 2 x u64)
#define TSY 64            // tile height
#define RPT 4             // rows per thread = TSY / 16

// sidecar layout (int32 units): seam s in 0..14 at column x=128(s+1):
//   A side (col x-1, right edge of tile bx=s)  : wsv[s*4096 + y]
//   B side (col x,   left  edge of tile bx=s+1): wsv[s*4096 + 2048 + y]
// 15*4096 ints = 240 KB. Every slot rewritten every call (bg writes 0).

// ---------- global union-find, 1-based parents, path-halving find ----------
// PLAIN loads: L1 may serve stale parents. SAFE because:
//  - a stale parent is a past ancestor -> same component (parents only
//    decrease, staying in-component);
//  - halving atomicMin(&L[a], g) with stale g only lowers toward a valid
//    ancestor (atomicMin never raises);
//  - a stale "root" is caught at attach: atomicMin is coherent, and on
//    failure we CONTINUE WITH the observed old parent, re-uniting through
//    it (Komura retry invariant) -- this also repairs severed links.
__device__ __forceinline__ int gfind(int* __restrict__ L, int a) {
    int n = L[a];
    while (n != a + 1) {
        int p = n - 1;
        int g = L[p];                     // grandparent+1 (possibly stale)
        // halving MUST be atomicMin: plain store could overwrite a
        // concurrent union's smaller parent. g is same-component & smaller.
        if (g != n) atomicMin(&L[a], g);
        a = p; n = g;
    }
    return a;
}

__device__ __forceinline__ void gunite(int* __restrict__ L, int a, int b) {
    while (true) {
        a = gfind(L, a);
        b = gfind(L, b);
        if (a == b) return;
        if (a > b) { int t = a; a = b; b = t; }
        int old = atomicMin(&L[b], a + 1);
        if (old == b + 1) return;   // attached larger root under smaller
        b = old - 1;                // raced/stale; continue from observed
    }                               // parent (repairs any severed link)
}

// ---------- local (LDS) union-find, 0-based, -1 = background ----------
__device__ __forceinline__ int lfind(volatile int* L, int a) {
    int n = L[a];
    while (n != a) { a = n; n = L[a]; }
    return a;
}

// find with atomicMin path-halving (safe under concurrent unions: parents
// only decrease and remain in-component)
__device__ __forceinline__ int lfind_h(int* L, int a) {
    volatile int* Lv = L;
    int n = Lv[a];
    while (n != a) {
        int g = Lv[n];
        if (g != n) atomicMin(&L[a], g);
        a = n; n = g;
    }
    return a;
}

__device__ __forceinline__ void lunite(int* L, int a, int b) {
    while (true) {
        a = lfind_h(L, a);
        b = lfind_h(L, b);
        if (a == b) return;
        if (a > b) { int t = a; a = b; b = t; }
        int old = atomicMin(&L[b], a);
        if (old == b) return;
        b = old;
    }
}

// run start (smallest s<=p with bits s..p all set; requires bit p set)
__device__ __forceinline__ int run_start64(unsigned long long m, int p) {
    if (p == 0) return 0;
    unsigned long long below = m << (64 - p);   // bit p-1 -> bit 63
    return p - __builtin_clzll(~below);         // minus count of leading ones
}

__device__ __forceinline__ int run_start128(unsigned long long u0,
                                            unsigned long long u1, int p) {
    if (p >= 64) {
        int s = run_start64(u1, p - 64) + 64;
        if (s == 64 && (u0 >> 63)) s = run_start64(u0, 63);  // continues left
        return s;
    }
    return run_start64(u0, p);
}

__device__ __forceinline__ int getbit128(unsigned long long u0,
                                         unsigned long long u1, int p) {
    if (p < 0 || p > 127) return 0;
    return (int)((p < 64 ? (u0 >> p) : (u1 >> (p - 64))) & 1ull);
}

__global__ __launch_bounds__(1024)
void k_local(const float* __restrict__ prob, int* __restrict__ lab,
             int* __restrict__ wsv) {
    __shared__ int slab[TSY * TSX];                       // 32 KB
    __shared__ unsigned long long mrow0[TSY], mrow1[TSY]; // 1 KB mask table
    const int x0 = blockIdx.x * TSX, y0 = blockIdx.y * TSY;
    const int lx = threadIdx.x;                 // 0..63 == lane
    const int ty = threadIdx.y;                 // 0..15

    unsigned long long rM0[RPT], rM1[RPT];
    int sA[RPT], sB[RPT];                       // run starts, register-cached

    // init: two ballots per row; label := row-global run start (kills all
    // horizontal unions, incl. across the 64-lane segment boundary)
    #pragma unroll
    for (int k = 0; k < RPT; ++k) {
        int ly = ty * RPT + k;
        const float* rowp = prob + (long)(y0 + ly) * W + x0;
        bool f0 = rowp[lx] > 0.5f;
        bool f1 = rowp[64 + lx] > 0.5f;
        unsigned long long m0 = __ballot(f0);
        unsigned long long m1 = __ballot(f1);
        rM0[k] = m0; rM1[k] = m1;
        int s0 = f0 ? run_start128(m0, m1, lx) : lx;
        int s1 = f1 ? run_start128(m0, m1, 64 + lx) : 64 + lx;
        sA[k] = s0; sB[k] = s1;
        slab[ly * TSX + lx]      = f0 ? ly * TSX + s0 : -1;
        slab[ly * TSX + 64 + lx] = f1 ? ly * TSX + s1 : -1;
        if (lx == 0) { mrow0[ly] = m0; mrow1[ly] = m1; }
    }
    __syncthreads();

    // vertical unions, once per (my-run, upper-segment) overlap.
    // Control uses ONLY register-cached / mask-table values (slab roots
    // mutate under concurrent lunite -- round-4 lesson).
    #pragma unroll
    for (int k = 0; k < RPT; ++k) {
        int ly = ty * RPT + k;
        if (ly == 0) continue;
        unsigned long long u0 = mrow0[ly - 1], u1 = mrow1[ly - 1];
        unsigned long long m0 = rM0[k], m1 = rM1[k];
        #pragma unroll
        for (int h = 0; h < 2; ++h) {
            int pos = h * 64 + lx;
            if (!getbit128(m0, m1, pos)) continue;
            int s = h ? sB[k] : sA[k];
            int mylab = ly * TSX + s;
            if (getbit128(u0, u1, pos)) {
                if (pos == s || !getbit128(u0, u1, pos - 1))
                    lunite(slab, mylab, (ly - 1) * TSX + run_start128(u0, u1, pos));
            } else {
                if (pos == s && getbit128(u0, u1, pos - 1))
                    lunite(slab, mylab, (ly - 1) * TSX + run_start128(u0, u1, pos - 1));
                bool isEnd = (pos == 127) || !getbit128(m0, m1, pos + 1);
                if (isEnd && getbit128(u0, u1, pos + 1))
                    lunite(slab, mylab, (ly - 1) * TSX + (pos + 1));
            }
        }
    }
    __syncthreads();

    // flatten step a: pre-flatten RUN-START entries only. Tree is static
    // now; plain stores write true roots.
    #pragma unroll
    for (int k = 0; k < RPT; ++k) {
        int ly = ty * RPT + k;
        unsigned long long m0 = rM0[k], m1 = rM1[k];
        if (((m0 >> lx) & 1) && sA[k] == lx) {
            int li = ly * TSX + lx;
            slab[li] = lfind(slab, li);
        }
        if (((m1 >> lx) & 1) && sB[k] == 64 + lx) {
            int li = ly * TSX + 64 + lx;
            slab[li] = lfind(slab, li);
        }
    }
    __syncthreads();

    // flatten step b: one LDS read at the register-cached run start
    // (same-run lanes hit one bank word -> broadcast). Edge labels also go
    // to the seam sidecar (coalesced consumption in k_seam).
    #pragma unroll
    for (int k = 0; k < RPT; ++k) {
        int ly = ty * RPT + k;
        unsigned long long m0 = rM0[k], m1 = rM1[k];
        int out0 = 0, out1 = 0;
        if ((m0 >> lx) & 1) {
            int r = slab[ly * TSX + sA[k]];
            out0 = (y0 + (r >> 7)) * W + (x0 + (r & 127)) + 1;
        }
        if ((m1 >> lx) & 1) {
            int r = slab[ly * TSX + sB[k]];
            out1 = (y0 + (r >> 7)) * W + (x0 + (r & 127)) + 1;
        }
        lab[(long)(y0 + ly) * W + x0 + lx]      = out0;
        lab[(long)(y0 + ly) * W + x0 + 64 + lx] = out1;
        if (lx == 0 && blockIdx.x > 0)            // left edge -> B side
            wsv[(blockIdx.x - 1) * 4096 + 2048 + (y0 + ly)] = out0;
        if (lx == 63 && blockIdx.x < 15)          // right edge -> A side
            wsv[blockIdx.x * 4096 + (y0 + ly)] = out1;
    }
}

// Cross-tile seam merge. 736 wave-tasks: 240 vertical (15 seam columns at
// x=128c, 16 chunks of 128 rows; labels from the CONTIGUOUS sidecar) +
// 496 horizontal (31 seam rows at y=64k, 16 chunks of 128 cols; rows are
// contiguous in lab). One gunite per (B-run, A-run) overlap segment:
//   covered    : leftmost pos of the A-segment inside my run
//   left-touch : my run start, A set only at pos-1 (in-chunk)
//   right-touch: my run end,  A set only at pos+1 (in-chunk)
// Chunks crossing perpendicular tile boundaries stay correct by
// transitivity (perpendicular seam unions supply the intra-run links).
__global__ __launch_bounds__(256)
void k_seam(int* __restrict__ lab, const int* __restrict__ wsv) {
    int gtid = blockIdx.x * blockDim.x + threadIdx.x;
    int task = gtid >> 6;
    int lane = gtid & 63;
    bool vertical = task < 240;
    int t = vertical ? task : task - 240;
    int seam = t >> 4, chunk = t & 15;

    const int* aPtr;
    const int* bPtr;
    int y_h = 0, xb_h = 0;
    if (vertical) {
        int ybase = chunk << 7;            // 128-row chunk
        aPtr = wsv + seam * 4096 + ybase;          // col x-1 labels
        bPtr = wsv + seam * 4096 + 2048 + ybase;   // col x   labels
    } else {
        y_h = (seam + 1) << 6;             // seam row (every 64)
        xb_h = chunk << 7;
        bPtr = lab + (long)y_h * W + xb_h;
        aPtr = bPtr - W;
    }
    int B0 = bPtr[lane], B1 = bPtr[64 + lane];
    int A0 = aPtr[lane], A1 = aPtr[64 + lane];

    unsigned long long m0 = __ballot(B0 != 0), m1 = __ballot(B1 != 0);
    unsigned long long u0 = __ballot(A0 != 0), u1 = __ballot(A1 != 0);

    #pragma unroll
    for (int h = 0; h < 2; ++h) {
        int pos = (h << 6) | lane;
        if (!getbit128(m0, m1, pos)) continue;
        int myB = h ? B1 : B0;
        int s = run_start128(m0, m1, pos);
        if (getbit128(u0, u1, pos)) {
            if (pos == s || !getbit128(u0, u1, pos - 1)) {
                int tgt = h ? A1 : A0;
                gunite(lab, myB - 1, tgt - 1);
            }
        } else {
            if (pos == s && pos > 0 && getbit128(u0, u1, pos - 1)) {
                gunite(lab, myB - 1, aPtr[pos - 1] - 1);
            }
            bool isEnd = (pos == 127) || !getbit128(m0, m1, pos + 1);
            if (isEnd && pos < 127 && getbit128(u0, u1, pos + 1)) {
                gunite(lab, myB - 1, aPtr[pos + 1] - 1);
            }
        }
    }

    // corner diagonal links (horizontal chunks only, edge lanes)
    if (!vertical && lane == 0) {
        if (xb_h > 0 && (m0 & 1) && !(u0 & 1)) {           // NW corner
            int tgt = lab[(long)(y_h - 1) * W + xb_h - 1];
            if (tgt) gunite(lab, B0 - 1, tgt - 1);
        }
        if (xb_h + 128 < W && ((m1 >> 63) & 1) && !((u1 >> 63) & 1)) {  // NE
            int tgt = lab[(long)(y_h - 1) * W + xb_h + 128];
            if (tgt) {
                int b127 = lab[(long)y_h * W + xb_h + 127];
                gunite(lab, b127 - 1, tgt - 1);
            }
        }
    }
}

// READ-ONLY compress: the union-find tree is static in this kernel, so no
// halving writes (4M atomicMins aimed at a few thousand root cachelines
// would serialize). Plain loads: kernel-launch boundary invalidates stale
// L1; in-kernel writes only store FINAL root values, which are themselves
// valid ancestors for any concurrent reader.
__global__ __launch_bounds__(256)
void k_compress(int* __restrict__ lab) {
    int i = blockIdx.x * blockDim.x + threadIdx.x;
    if (i >= NPIX) return;
    int v = lab[i];
    if (v == 0) return;                  // bg
    int a = v - 1;
    int n = lab[a];
    while (n != a + 1) { a = n - 1; n = lab[a]; }
    if (a + 1 != v) lab[i] = a + 1;      // root+1 is the component min
}

extern "C" void kernel_launch(void* const* d_in, const int* in_sizes, int n_in,
                              void* d_out, int out_size, void* d_ws, size_t ws_size,
                              hipStream_t stream) {
    const float* prob = (const float*)d_in[0];
    int* lab = (int*)d_out;
    int* wsv = (int*)d_ws;               // 240 KB sidecar (ws is >= that)

    dim3 lgrid(W / TSX, H / TSY);        // 16 x 32 = 512 blocks (2/CU)
    dim3 lblock(64, 16);                 // 1024 threads, 16 waves
    k_local<<<lgrid, lblock, 0, stream>>>(prob, lab, wsv);

    // 736 wave-tasks * 64 lanes = 47104 threads = 184 blocks exactly
    k_seam<<<184, 256, 0, stream>>>(lab, wsv);

    k_compress<<<NPIX / 256, 256, 0, stream>>>(lab);
}